// Round 1
// baseline (310.640 us; speedup 1.0000x reference)
//
#include <hip/hip_runtime.h>
#include <math.h>

#define AN 4096
#define CN 8
#define FN 64
#define ACN (AN*CN)   // 32768

// ---------------------------------------------------------------------------
// K1: normalize rows of x (A*C vectors of F floats) -> xn [a][c][f]
//     and transposed xnT [c][f][a] for the GEMM staging.
// 16 lanes per vector, float4 loads. 2048 blocks x 256 threads.
// ---------------------------------------------------------------------------
__global__ __launch_bounds__(256) void k1_normalize(const float* __restrict__ x,
                                                    float* __restrict__ xn,
                                                    float* __restrict__ xnT)
{
    int tid  = threadIdx.x;
    int grp  = tid >> 4;       // 0..15  (vector within block)
    int slot = tid & 15;       // float4 slot within vector
    int V = blockIdx.x * 16 + grp;          // 0..32767
    const float4 v = *(const float4*)(x + (size_t)V * FN + slot * 4);
    float ss = v.x*v.x + v.y*v.y + v.z*v.z + v.w*v.w;
    // reduce across the 16 lanes of this vector (16-aligned groups)
    ss += __shfl_xor(ss, 1);
    ss += __shfl_xor(ss, 2);
    ss += __shfl_xor(ss, 4);
    ss += __shfl_xor(ss, 8);
    float nrm = sqrtf(ss);
    float sc = 1.0f / fmaxf(nrm, 1e-6f);
    float4 o; o.x = v.x*sc; o.y = v.y*sc; o.z = v.z*sc; o.w = v.w*sc;
    *(float4*)(xn + (size_t)V * FN + slot * 4) = o;
    int a = V >> 3, c = V & 7;
    float* base = xnT + ((size_t)c * FN + slot * 4) * AN + a;
    base[0]      = o.x;
    base[AN]     = o.y;
    base[2*AN]   = o.z;
    base[3*AN]   = o.w;
}

// ---------------------------------------------------------------------------
// K2: per-channel sim + rolling argmax.
// Grid: 512 blocks = 8 channels x 32 row-tiles x 2 b-halves. 128 threads.
// Block: rows [a0, a0+128), cols b in [half*2048, half*2048+2048) via 16
// tiles of 128. LDS tiles k-major [64][128] (stride 128 floats: compute
// reads <=2-way conflict, staging b128 writes hit all 32 banks).
// Micro-tile per thread: 16 rows x 8 cols.
// ---------------------------------------------------------------------------
__global__ __launch_bounds__(128, 1) void k2_argmax(const float* __restrict__ xnT,
                                                    float* __restrict__ pS,
                                                    int* __restrict__ pI)
{
    __shared__ float smem[2 * FN * 128];   // 64 KB: At then Bt
    float* At = smem;
    float* Bt = smem + FN * 128;

    int blk  = blockIdx.x;
    int half = blk & 1;
    int rt   = (blk >> 1) & 31;
    int c    = blk >> 6;
    int a0   = rt * 128;

    const float* Xc = xnT + (size_t)c * FN * AN;   // [f][a]

    int tid  = threadIdx.x;
    int lane = tid & 63;
    int wq   = tid >> 6;        // wave id 0..1
    int tx   = tid & 15;        // col group
    int ty   = tid >> 4;        // row group 0..7

    // ---- stage A tile once: At[f][r] = Xc[f][a0+r] ----
    {
        int lx = 4 * (lane & 15) + 64 * wq;   // 0..124 step 4
        int fb = lane >> 4;                   // 0..3
        #pragma unroll
        for (int m = 0; m < 16; ++m) {
            int f = 4 * m + fb;
            float4 v = *(const float4*)(Xc + (size_t)f * AN + a0 + lx);
            *(float4*)&At[f * 128 + lx] = v;
        }
    }

    float best[16];
    int   bidx[16];
    #pragma unroll
    for (int i = 0; i < 16; ++i) { best[i] = -INFINITY; bidx[i] = 0; }

    for (int bt = 0; bt < 16; ++bt) {
        int b0 = half * 2048 + bt * 128;
        __syncthreads();
        // ---- stage B tile ----
        {
            int lx = 4 * (lane & 15) + 64 * wq;
            int fb = lane >> 4;
            #pragma unroll
            for (int m = 0; m < 16; ++m) {
                int f = 4 * m + fb;
                float4 v = *(const float4*)(Xc + (size_t)f * AN + b0 + lx);
                *(float4*)&Bt[f * 128 + lx] = v;
            }
        }
        __syncthreads();

        float acc[16][8];
        #pragma unroll
        for (int i = 0; i < 16; ++i)
            #pragma unroll
            for (int j = 0; j < 8; ++j) acc[i][j] = 0.0f;

        #pragma unroll 4
        for (int k = 0; k < FN; ++k) {
            float ar[16], br[8];
            #pragma unroll
            for (int g = 0; g < 4; ++g) {
                float4 av = *(const float4*)&At[k * 128 + 32 * g + 4 * ty];
                ar[4*g+0] = av.x; ar[4*g+1] = av.y; ar[4*g+2] = av.z; ar[4*g+3] = av.w;
            }
            float4 bv0 = *(const float4*)&Bt[k * 128 + 4 * tx];
            float4 bv1 = *(const float4*)&Bt[k * 128 + 64 + 4 * tx];
            br[0] = bv0.x; br[1] = bv0.y; br[2] = bv0.z; br[3] = bv0.w;
            br[4] = bv1.x; br[5] = bv1.y; br[6] = bv1.z; br[7] = bv1.w;
            #pragma unroll
            for (int i = 0; i < 16; ++i)
                #pragma unroll
                for (int j = 0; j < 8; ++j)
                    acc[i][j] = fmaf(ar[i], br[j], acc[i][j]);
        }

        // ---- rolling argmax update (diag excluded) ----
        #pragma unroll
        for (int i16 = 0; i16 < 16; ++i16) {
            int g = i16 >> 2, i = i16 & 3;
            int aglob = a0 + 32 * g + 4 * ty + i;
            #pragma unroll
            for (int j = 0; j < 8; ++j) {
                int col = (j < 4) ? (4 * tx + j) : (64 + 4 * tx + (j - 4));
                int bglob = b0 + col;
                float s = acc[i16][j];
                if ((bglob != aglob) && (s > best[i16])) {
                    best[i16] = s; bidx[i16] = bglob;
                }
            }
        }
    }

    // ---- cross-tx reduce per row (tie -> smaller index) ----
    __syncthreads();
    float* redS = smem;                 // [128][16]
    int*   redI = (int*)&smem[128 * 16];
    #pragma unroll
    for (int i16 = 0; i16 < 16; ++i16) {
        int g = i16 >> 2, i = i16 & 3;
        int r = 32 * g + 4 * ty + i;
        redS[r * 16 + tx] = best[i16];
        redI[r * 16 + tx] = bidx[i16];
    }
    __syncthreads();
    if (tid < 128) {
        int r = tid;
        float bs = redS[r * 16];
        int   bi = redI[r * 16];
        #pragma unroll
        for (int t = 1; t < 16; ++t) {
            float s = redS[r * 16 + t];
            int  i2 = redI[r * 16 + t];
            if (s > bs || (s == bs && i2 < bi)) { bs = s; bi = i2; }
        }
        int a = a0 + r;
        pS[(size_t)half * ACN + a * CN + c] = bs;
        pI[(size_t)half * ACN + a * CN + c] = bi;
    }
}

// ---------------------------------------------------------------------------
// K3: merge halves, gather matched vector, fp32 distance + log, block-reduce.
// 128 blocks x 256 threads, one thread per (a,c).
// ---------------------------------------------------------------------------
__global__ __launch_bounds__(256) void k3_dist(const float* __restrict__ xn,
                                               const float* __restrict__ pS,
                                               const int* __restrict__ pI,
                                               float* __restrict__ partials)
{
    int id = blockIdx.x * 256 + threadIdx.x;   // a*8 + c
    float s0 = pS[id], s1 = pS[ACN + id];
    int   i0 = pI[id], i1 = pI[ACN + id];
    int m = (s0 >= s1) ? i0 : i1;              // tie -> half0 (smaller index)
    int c = id & 7;
    const float* xa = xn + (size_t)id * FN;
    const float* xb = xn + ((size_t)m * CN + c) * FN;
    float ss = 0.0f;
    #pragma unroll
    for (int q = 0; q < 16; ++q) {
        float4 va = *(const float4*)(xa + 4 * q);
        float4 vb = *(const float4*)(xb + 4 * q);
        float d0 = va.x - vb.x + 1e-6f;
        float d1 = va.y - vb.y + 1e-6f;
        float d2 = va.z - vb.z + 1e-6f;
        float d3 = va.w - vb.w + 1e-6f;
        ss += d0*d0 + d1*d1 + d2*d2 + d3*d3;
    }
    float dist = sqrtf(ss);
    float val = logf(dist + 1e-6f);

    float t = val;
    #pragma unroll
    for (int off = 32; off > 0; off >>= 1) t += __shfl_down(t, off);
    __shared__ float ws4[4];
    if ((threadIdx.x & 63) == 0) ws4[threadIdx.x >> 6] = t;
    __syncthreads();
    if (threadIdx.x == 0)
        partials[blockIdx.x] = ws4[0] + ws4[1] + ws4[2] + ws4[3];
}

// ---------------------------------------------------------------------------
// K4: final scalar: out = -sum(partials)/32768
// ---------------------------------------------------------------------------
__global__ __launch_bounds__(64) void k4_final(const float* __restrict__ partials,
                                               float* __restrict__ out)
{
    int t = threadIdx.x;   // 64 threads
    float v = partials[t] + partials[t + 64];
    #pragma unroll
    for (int off = 32; off > 0; off >>= 1) v += __shfl_down(v, off);
    if (t == 0) out[0] = -v / (float)ACN;
}

extern "C" void kernel_launch(void* const* d_in, const int* in_sizes, int n_in,
                              void* d_out, int out_size, void* d_ws, size_t ws_size,
                              hipStream_t stream)
{
    const float* x = (const float*)d_in[0];
    float* ws = (float*)d_ws;
    float* xn   = ws;                              // 2,097,152 floats
    float* xnT  = xn + (size_t)AN * CN * FN;       // 2,097,152 floats
    float* pS   = xnT + (size_t)AN * CN * FN;      // 65,536 floats
    float* pIf  = pS + 2 * ACN;                    // 65,536 ints
    int*   pI   = (int*)pIf;
    float* partials = pIf + 2 * ACN;               // 128 floats

    k1_normalize<<<2048, 256, 0, stream>>>(x, xn, xnT);
    k2_argmax  <<<512, 128, 0, stream>>>(xnT, pS, pI);
    k3_dist    <<<128, 256, 0, stream>>>(xn, pS, pI, partials);
    k4_final   <<<1, 64, 0, stream>>>(partials, (float*)d_out);
}

// Round 2
// 93.567 us; speedup vs baseline: 3.3200x; 3.3200x over previous
//
#include <hip/hip_runtime.h>
#include <math.h>

#define AN 4096
#define CN 8
#define FN 64
#define ACN (AN*CN)   // 32768

typedef __attribute__((ext_vector_type(8))) short bf16x8;
typedef __attribute__((ext_vector_type(4))) float f32x4;

__device__ inline unsigned short f2bf(float f) {
    unsigned u = __float_as_uint(f);
    unsigned r = ((u >> 16) & 1) + 0x7FFFu;   // round-to-nearest-even
    return (unsigned short)((u + r) >> 16);
}

// ---------------------------------------------------------------------------
// K1: normalize -> xn fp32 [a][c][f] (for exact distance in k3)
//               -> xnb bf16 [c][a][f] row-major per channel (for MFMA in k2)
// ---------------------------------------------------------------------------
__global__ __launch_bounds__(256) void k1_normalize(const float* __restrict__ x,
                                                    float* __restrict__ xn,
                                                    unsigned short* __restrict__ xnb)
{
    int tid  = threadIdx.x;
    int grp  = tid >> 4;
    int slot = tid & 15;
    int V = blockIdx.x * 16 + grp;          // 0..32767 = a*8+c
    const float4 v = *(const float4*)(x + (size_t)V * FN + slot * 4);
    float ss = v.x*v.x + v.y*v.y + v.z*v.z + v.w*v.w;
    ss += __shfl_xor(ss, 1);
    ss += __shfl_xor(ss, 2);
    ss += __shfl_xor(ss, 4);
    ss += __shfl_xor(ss, 8);
    float sc = 1.0f / fmaxf(sqrtf(ss), 1e-6f);
    float4 o; o.x = v.x*sc; o.y = v.y*sc; o.z = v.z*sc; o.w = v.w*sc;
    *(float4*)(xn + (size_t)V * FN + slot * 4) = o;
    int a = V >> 3, c = V & 7;
    ushort4 ob;
    ob.x = f2bf(o.x); ob.y = f2bf(o.y); ob.z = f2bf(o.z); ob.w = f2bf(o.w);
    *(ushort4*)(xnb + ((size_t)c * AN + a) * FN + slot * 4) = ob;
}

// ---------------------------------------------------------------------------
// K2: MFMA sim + in-register packed argmax.
// Grid 512 = 8 channels x 32 row-tiles x 2 col-halves. 256 threads = 4 waves
// in 2x2 quadrants (64 rows x 64 cols each). Tile: 128 rows x 128 cols x K=64
// per col-iter, 16 iters. A-frags register-resident; B double-buffered in LDS.
// LDS 16B chunks XOR-swizzled by (row&7): staging writes and frag reads are
// <=2-way bank-aliased (free, m136).
// Packed argmax: acc initialized to 2.0 (s' = 2+sim in [1,3] > 0); packed =
// (bits(s') & ~0xFFF) | col; float-max == lexicographic (quantized s', col).
// Diagonal excluded by zeroing the packed candidate on the diag fragment.
// ---------------------------------------------------------------------------
__global__ __launch_bounds__(256, 2) void k2_argmax(const unsigned short* __restrict__ xnb,
                                                    unsigned int* __restrict__ pP)
{
    __shared__ uint4 lds4[3 * 1024];   // At [0,1024) | Bt0 [1024,2048) | Bt1 [2048,3072)

    int blk  = blockIdx.x;
    int half = blk & 1;
    int rt   = (blk >> 1) & 31;
    int c    = blk >> 6;
    int a0   = rt * 128;
    int b0base = half * 2048;

    const uint4* __restrict__ Xc4 = (const uint4*)(xnb + (size_t)c * AN * FN); // row r, chunk q -> [r*8+q]

    int tid  = threadIdx.x;
    int lane = tid & 63;
    int w    = tid >> 6;
    int wr   = w >> 1;        // row quadrant 0..1
    int wc   = w & 1;         // col quadrant 0..1
    int l15  = lane & 15;
    int quad = lane >> 4;

    int srow   = tid >> 3;    // staging row base 0..31
    int schunk = tid & 7;     // staging 16B chunk 0..7

    // ---- stage A tile (rows a0..a0+127) ----
    #pragma unroll
    for (int s = 0; s < 4; ++s) {
        int r = srow + 32 * s;
        lds4[r * 8 + (schunk ^ (r & 7))] = Xc4[(size_t)(a0 + r) * 8 + schunk];
    }
    // ---- stage B tile 0 ----
    #pragma unroll
    for (int s = 0; s < 4; ++s) {
        int r = srow + 32 * s;
        lds4[1024 + r * 8 + (schunk ^ (r & 7))] = Xc4[(size_t)(b0base + r) * 8 + schunk];
    }
    __syncthreads();

    // ---- A fragments into registers (loop-invariant) ----
    bf16x8 afr[4][2];
    #pragma unroll
    for (int mi = 0; mi < 4; ++mi)
        #pragma unroll
        for (int ks = 0; ks < 2; ++ks) {
            int r  = wr * 64 + mi * 16 + l15;
            int ch = (ks * 4 + quad) ^ (r & 7);
            afr[mi][ks] = ((const bf16x8*)lds4)[r * 8 + ch];
        }

    float bestp[16];
    #pragma unroll
    for (int i = 0; i < 16; ++i) bestp[i] = 0.0f;

    const f32x4 two = {2.0f, 2.0f, 2.0f, 2.0f};

    for (int it = 0; it < 16; ++it) {
        int cur = it & 1;
        // prefetch next B tile into registers
        uint4 gv[4];
        if (it < 15) {
            int g0 = b0base + (it + 1) * 128;
            #pragma unroll
            for (int s = 0; s < 4; ++s)
                gv[s] = Xc4[(size_t)(g0 + srow + 32 * s) * 8 + schunk];
        }

        // ---- MFMA on buffer cur ----
        f32x4 acc[4][4];
        const bf16x8* bt = (const bf16x8*)(lds4 + 1024 + cur * 1024);
        #pragma unroll
        for (int ks = 0; ks < 2; ++ks) {
            #pragma unroll
            for (int ni = 0; ni < 4; ++ni) {
                int r  = wc * 64 + ni * 16 + l15;
                int ch = (ks * 4 + quad) ^ (r & 7);
                bf16x8 bfr = bt[r * 8 + ch];
                #pragma unroll
                for (int mi = 0; mi < 4; ++mi)
                    acc[mi][ni] = __builtin_amdgcn_mfma_f32_16x16x32_bf16(
                        afr[mi][ks], bfr, (ks == 0) ? two : acc[mi][ni], 0, 0, 0);
            }
        }

        // ---- packed argmax update ----
        int colblk = b0base + it * 128 + wc * 64;
        #pragma unroll
        for (int ni = 0; ni < 4; ++ni) {
            int cfrag = colblk + ni * 16;
            unsigned code = (unsigned)(cfrag + l15);
            #pragma unroll
            for (int mi = 0; mi < 4; ++mi) {
                int rfrag = a0 + wr * 64 + mi * 16;
                bool dg = (rfrag == cfrag);          // wave-uniform
                #pragma unroll
                for (int r = 0; r < 4; ++r) {
                    unsigned pb = (__float_as_uint(acc[mi][ni][r]) & 0xFFFFF000u) | code;
                    if (dg && (l15 == quad * 4 + r)) pb = 0u;   // exclude diagonal
                    int bi = mi * 4 + r;
                    bestp[bi] = fmaxf(bestp[bi], __uint_as_float(pb));
                }
            }
        }

        // ---- write prefetched tile into other buffer ----
        if (it < 15) {
            #pragma unroll
            for (int s = 0; s < 4; ++s) {
                int r = srow + 32 * s;
                lds4[1024 + (cur ^ 1) * 1024 + r * 8 + (schunk ^ (r & 7))] = gv[s];
            }
        }
        __syncthreads();
    }

    // ---- reduce across the 16 column-lanes ----
    #pragma unroll
    for (int i = 0; i < 16; ++i) {
        float v = bestp[i];
        v = fmaxf(v, __shfl_xor(v, 1));
        v = fmaxf(v, __shfl_xor(v, 2));
        v = fmaxf(v, __shfl_xor(v, 4));
        v = fmaxf(v, __shfl_xor(v, 8));
        bestp[i] = v;
    }
    __syncthreads();                    // At region now reusable
    float* red = (float*)lds4;          // red[w][64]
    if (l15 == 0) {
        #pragma unroll
        for (int mi = 0; mi < 4; ++mi)
            #pragma unroll
            for (int r = 0; r < 4; ++r)
                red[w * 64 + mi * 16 + quad * 4 + r] = bestp[mi * 4 + r];
    }
    __syncthreads();
    if (tid < 128) {
        int wr2 = tid >> 6, r64 = tid & 63;
        float p = fmaxf(red[(2 * wr2) * 64 + r64], red[(2 * wr2 + 1) * 64 + r64]);
        int a = a0 + tid;
        pP[(size_t)half * ACN + (size_t)a * CN + c] = __float_as_uint(p);
    }
}

// ---------------------------------------------------------------------------
// K3: merge halves, unpack index, exact fp32 distance + log, block-reduce.
// ---------------------------------------------------------------------------
__global__ __launch_bounds__(256) void k3_dist(const float* __restrict__ xn,
                                               const unsigned int* __restrict__ pP,
                                               float* __restrict__ partials)
{
    int id = blockIdx.x * 256 + threadIdx.x;   // a*8 + c
    float p0 = __uint_as_float(pP[id]);
    float p1 = __uint_as_float(pP[ACN + id]);
    unsigned pm = __float_as_uint(fmaxf(p0, p1));
    int m = (int)(pm & 0xFFFu);
    int c = id & 7;
    const float* xa = xn + (size_t)id * FN;
    const float* xb = xn + ((size_t)m * CN + c) * FN;
    float ss = 0.0f;
    #pragma unroll
    for (int q = 0; q < 16; ++q) {
        float4 va = *(const float4*)(xa + 4 * q);
        float4 vb = *(const float4*)(xb + 4 * q);
        float d0 = va.x - vb.x + 1e-6f;
        float d1 = va.y - vb.y + 1e-6f;
        float d2 = va.z - vb.z + 1e-6f;
        float d3 = va.w - vb.w + 1e-6f;
        ss += d0*d0 + d1*d1 + d2*d2 + d3*d3;
    }
    float val = logf(sqrtf(ss) + 1e-6f);

    float t = val;
    #pragma unroll
    for (int off = 32; off > 0; off >>= 1) t += __shfl_down(t, off);
    __shared__ float ws4[4];
    if ((threadIdx.x & 63) == 0) ws4[threadIdx.x >> 6] = t;
    __syncthreads();
    if (threadIdx.x == 0)
        partials[blockIdx.x] = ws4[0] + ws4[1] + ws4[2] + ws4[3];
}

// ---------------------------------------------------------------------------
// K4: out = -sum(partials)/32768
// ---------------------------------------------------------------------------
__global__ __launch_bounds__(64) void k4_final(const float* __restrict__ partials,
                                               float* __restrict__ out)
{
    int t = threadIdx.x;
    float v = partials[t] + partials[t + 64];
    #pragma unroll
    for (int off = 32; off > 0; off >>= 1) v += __shfl_down(v, off);
    if (t == 0) out[0] = -v / (float)ACN;
}

extern "C" void kernel_launch(void* const* d_in, const int* in_sizes, int n_in,
                              void* d_out, int out_size, void* d_ws, size_t ws_size,
                              hipStream_t stream)
{
    const float* x = (const float*)d_in[0];
    float* ws = (float*)d_ws;
    float* xn = ws;                                       // 2,097,152 floats (8 MB)
    unsigned short* xnb = (unsigned short*)(xn + (size_t)AN * CN * FN);  // 4 MB
    unsigned int* pP = (unsigned int*)(xnb + (size_t)AN * CN * FN);      // 2*32768 uints
    float* partials = (float*)(pP + 2 * ACN);             // 128 floats

    k1_normalize<<<2048, 256, 0, stream>>>(x, xn, xnb);
    k2_argmax  <<<512, 256, 0, stream>>>(xnb, pP);
    k3_dist    <<<128, 256, 0, stream>>>(xn, pP, partials);
    k4_final   <<<1, 64, 0, stream>>>(partials, (float*)d_out);
}